// Round 9
// baseline (99.334 us; speedup 1.0000x reference)
//
#include <hip/hip_runtime.h>
#include <math.h>

#define IMG    512
#define TWD    32        // tile width
#define NSTRIP 4         // 32-row strips per block
#define BROWS  128       // output rows per block
#define WIN    42        // rolling hb window rows
#define HS     36        // hb row stride: 144B (16B-aligned), 36%32=4
#define NBLK   3072      // 16 * 4 * 48
#define NPIX   12582912.0

// Normalized 11-tap Gaussian, sigma=1.5 — inline literals
constexpr float G[11] = {
    0.00102838f, 0.00759876f, 0.03600077f, 0.10936069f, 0.21300554f,
    0.26601173f,
    0.21300554f, 0.10936069f, 0.03600077f, 0.00759876f, 0.00102838f};

// hb planes: 0=mean(x) 1=mean(y) 2=mean(x^2+y^2) 3=mean(xy)
// buffer row b holds h-conv of global row (strip_base - 5 + b)
__global__ __launch_bounds__(128, 3) void ssim_tile_kernel(
    const float* __restrict__ x, const float* __restrict__ y,
    float* __restrict__ partial)
{
    __shared__ float hb[4][WIN][HS];    // 23.6 KB -> 6 blocks/CU
    __shared__ float wsum[2];

    const int tid = threadIdx.x;
    const int bx = blockIdx.x, by = blockIdx.y;
    const int c0 = bx * TWD;
    const int rbase0 = by * BROWS;
    const size_t ioff = (size_t)blockIdx.z * IMG * IMG;
    const float* __restrict__ xb = x + ioff;
    const float* __restrict__ yb = y + ioff;

    const bool icol = (bx > 0) & (bx < 15);

    // h-task: 4 outputs (cols 4g..4g+3) of global row grow -> buffer row bufrow
    auto htask = [&](int bufrow, int grow, int g) {
        const int cc0 = 4 * g;
        if ((unsigned)grow >= IMG) {    // zero-pad rows outside image
            float4 z4 = make_float4(0.f, 0.f, 0.f, 0.f);
#pragma unroll
            for (int q = 0; q < 4; ++q)
                *(float4*)&hb[q][bufrow][cc0] = z4;
            return;
        }
        const int gc0 = c0 - 8 + cc0;   // first of 20 raw cols
        float wx[20], wy[20];
        if (icol) {
            const float* __restrict__ px = xb + grow * IMG + gc0;
            const float* __restrict__ py = yb + grow * IMG + gc0;
#pragma unroll
            for (int i = 0; i < 5; ++i) {
                float4 fx = *(const float4*)(px + 4 * i);
                float4 fy = *(const float4*)(py + 4 * i);
                wx[4*i+0] = fx.x; wx[4*i+1] = fx.y; wx[4*i+2] = fx.z; wx[4*i+3] = fx.w;
                wy[4*i+0] = fy.x; wy[4*i+1] = fy.y; wy[4*i+2] = fy.z; wy[4*i+3] = fy.w;
            }
        } else {
            const float* __restrict__ px = xb + grow * IMG;
            const float* __restrict__ py = yb + grow * IMG;
#pragma unroll
            for (int i = 0; i < 5; ++i) {
                int gc = gc0 + 4 * i;
                if (gc >= 0 && gc + 3 < IMG) {
                    float4 fx = *(const float4*)(px + gc);
                    float4 fy = *(const float4*)(py + gc);
                    wx[4*i+0] = fx.x; wx[4*i+1] = fx.y; wx[4*i+2] = fx.z; wx[4*i+3] = fx.w;
                    wy[4*i+0] = fy.x; wy[4*i+1] = fy.y; wy[4*i+2] = fy.z; wy[4*i+3] = fy.w;
                } else {
#pragma unroll
                    for (int e = 0; e < 4; ++e) {
                        int c = gc + e;
                        bool ok = ((unsigned)c < IMG);
                        wx[4*i+e] = ok ? px[c] : 0.f;
                        wy[4*i+e] = ok ? py[c] : 0.f;
                    }
                }
            }
        }
        float pss[14], pxy[14];         // shared products, raw cols 3..16
#pragma unroll
        for (int j = 0; j < 14; ++j) {
            float a = wx[j + 3], b = wy[j + 3];
            pss[j] = fmaf(a, a, b * b);
            pxy[j] = a * b;
        }
        float ax[4] = {}, ay[4] = {}, ass[4] = {}, axy[4] = {};
#pragma unroll
        for (int e = 0; e < 4; ++e)
#pragma unroll
            for (int k = 0; k < 11; ++k) {
                ax[e]  = fmaf(G[k], wx[e + k + 3], ax[e]);
                ay[e]  = fmaf(G[k], wy[e + k + 3], ay[e]);
                ass[e] = fmaf(G[k], pss[e + k], ass[e]);
                axy[e] = fmaf(G[k], pxy[e + k], axy[e]);
            }
        *(float4*)&hb[0][bufrow][cc0] = make_float4(ax[0], ax[1], ax[2], ax[3]);
        *(float4*)&hb[1][bufrow][cc0] = make_float4(ay[0], ay[1], ay[2], ay[3]);
        *(float4*)&hb[2][bufrow][cc0] = make_float4(ass[0], ass[1], ass[2], ass[3]);
        *(float4*)&hb[3][bufrow][cc0] = make_float4(axy[0], axy[1], axy[2], axy[3]);
    };

    const int cg = tid & 15;            // col pair: cols 2cg, 2cg+1
    const int rb = (tid >> 4) * 4;      // v-pass rows rb..rb+3 (rg 0..7)
    float lsum = 0.f;

    for (int s = 0; s < NSTRIP; ++s) {
        const int sbase = rbase0 + 32 * s;
        if (s == 0) {
            // fill all 42 buffer rows: 336 tasks
            htask(tid >> 3, sbase - 5 + (tid >> 3), tid & 7);
            {
                int t = tid + 128;
                htask(t >> 3, sbase - 5 + (t >> 3), t & 7);
            }
            if (tid < 80) {
                int t = tid + 256;
                htask(t >> 3, sbase - 5 + (t >> 3), t & 7);
            }
        } else {
            // carry rows 32..41 -> 0..9 : 320 float4 moves (16B-aligned)
#pragma unroll
            for (int k = 0; k < 3; ++k) {
                int idx = tid + k * 128;
                if (idx < 320) {
                    int q = idx / 80, rem = idx - q * 80;
                    int rr = rem >> 3, c4 = rem & 7;
                    *(float4*)&hb[q][rr][4 * c4] =
                        *(const float4*)&hb[q][32 + rr][4 * c4];
                }
            }
            __syncthreads();
            // 32 new h-rows into buffer rows 10..41: 2 tasks/thread
            htask(10 + (tid >> 3), sbase + 5 + (tid >> 3), tid & 7);
            {
                int t = tid + 128;
                htask(10 + (t >> 3), sbase + 5 + (t >> 3), t & 7);
            }
        }
        __syncthreads();

        // v-pass: 2 cols x 4 rows per thread, float2 LDS reads
        float vr[4][4][2];
#pragma unroll
        for (int q = 0; q < 4; ++q)
#pragma unroll
            for (int j = 0; j < 4; ++j) { vr[q][j][0] = 0.f; vr[q][j][1] = 0.f; }
#pragma unroll
        for (int q = 0; q < 4; ++q)
#pragma unroll
            for (int k = 0; k < 14; ++k) {
                float2 v = *(const float2*)&hb[q][rb + k][2 * cg];
#pragma unroll
                for (int j = 0; j < 4; ++j)
                    if (k - j >= 0 && k - j <= 10) {
                        vr[q][j][0] = fmaf(G[k - j], v.x, vr[q][j][0]);
                        vr[q][j][1] = fmaf(G[k - j], v.y, vr[q][j][1]);
                    }
            }
#pragma unroll
        for (int j = 0; j < 4; ++j)
#pragma unroll
            for (int e = 0; e < 2; ++e) {
                float mx = vr[0][j][e], my = vr[1][j][e];
                float mss = vr[2][j][e], mxy = vr[3][j][e];
                float mx2 = mx * mx, my2 = my * my, mxmy = mx * my;
                float num = (2.f * mxmy + 0.0001f) * (2.f * (mxy - mxmy) + 0.0009f);
                float den = (mx2 + my2 + 0.0001f) * ((mss - mx2 - my2) + 0.0009f);
                lsum += num * __builtin_amdgcn_rcpf(den);
            }
        __syncthreads();   // protect window before next strip's carry
    }

    // ---- block reduction (2 waves) -> plain store ----
#pragma unroll
    for (int off = 32; off > 0; off >>= 1)
        lsum += __shfl_down(lsum, off, 64);
    if ((tid & 63) == 0) wsum[tid >> 6] = lsum;
    __syncthreads();
    if (tid == 0) {
        int bid = bx + 16 * (by + 4 * blockIdx.z);
        partial[bid] = wsum[0] + wsum[1];
    }
}

__global__ __launch_bounds__(1024) void ssim_reduce_kernel(
    const float* __restrict__ partial, float* __restrict__ out)
{
    __shared__ double ws[16];
    const int tid = threadIdx.x;
    double s = 0.0;
#pragma unroll
    for (int i = 0; i < NBLK / 1024; ++i) s += (double)partial[tid + i * 1024];
#pragma unroll
    for (int off = 32; off > 0; off >>= 1)
        s += __shfl_down(s, off, 64);
    if ((tid & 63) == 0) ws[tid >> 6] = s;
    __syncthreads();
    if (tid == 0) {
        double t = 0.0;
#pragma unroll
        for (int w = 0; w < 16; ++w) t += ws[w];
        double mean = t / NPIX;
        out[0] = (float)(-log10(mean));  // loss
        out[1] = (float)mean;            // ssim_mean
    }
}

extern "C" void kernel_launch(void* const* d_in, const int* in_sizes, int n_in,
                              void* d_out, int out_size, void* d_ws, size_t ws_size,
                              hipStream_t stream)
{
    const float* x = (const float*)d_in[0];
    const float* y = (const float*)d_in[1];
    float* out     = (float*)d_out;
    float* partial = (float*)d_ws;      // 3072 floats, fully rewritten each call

    dim3 grid(16, 4, 48);               // 3072 blocks, 128 threads (2 waves)
    ssim_tile_kernel<<<grid, 128, 0, stream>>>(x, y, partial);
    ssim_reduce_kernel<<<1, 1024, 0, stream>>>(partial, out);
}

// Round 10
// 87.073 us; speedup vs baseline: 1.1408x; 1.1408x over previous
//
#include <hip/hip_runtime.h>
#include <math.h>

#define IMG    512
#define TWD    64        // tile width
#define NSTRIP 8         // 32-row strips per block
#define BROWS  256       // output rows per block
#define WIN    42        // rolling hb window rows
#define HS     68        // hb row stride: 272B (16B-aligned), 68%32=4
#define NBLK   768       // 8 * 2 * 48
#define NPIX   12582912.0

// Normalized 11-tap Gaussian, sigma=1.5 — inline literals
constexpr float G[11] = {
    0.00102838f, 0.00759876f, 0.03600077f, 0.10936069f, 0.21300554f,
    0.26601173f,
    0.21300554f, 0.10936069f, 0.03600077f, 0.00759876f, 0.00102838f};

// hb planes: 0=mean(x) 1=mean(y) 2=mean(x^2+y^2) 3=mean(xy)
// buffer row b holds h-conv of global row (strip_base - 5 + b)
__global__ __launch_bounds__(256, 3) void ssim_tile_kernel(
    const float* __restrict__ x, const float* __restrict__ y,
    float* __restrict__ partial)
{
    __shared__ float hb[4][WIN][HS];    // 45.7 KB -> 3 blocks/CU
    __shared__ float wsum[4];

    const int tid = threadIdx.x;
    const int bx = blockIdx.x, by = blockIdx.y;
    const int c0 = bx * TWD;
    const int rbase0 = by * BROWS;
    const size_t ioff = (size_t)blockIdx.z * IMG * IMG;
    const float* __restrict__ xb = x + ioff;
    const float* __restrict__ yb = y + ioff;

    const bool icol = (bx > 0) & (bx < 7);

    // h-task: 4 outputs (cols 4g..4g+3) of global row grow -> buffer row bufrow
    // live set ~84 floats (R7-proven no-spill shape)
    auto htask = [&](int bufrow, int grow, int g) {
        const int cc0 = 4 * g;
        if ((unsigned)grow >= IMG) {    // zero-pad rows outside image
            float4 z4 = make_float4(0.f, 0.f, 0.f, 0.f);
#pragma unroll
            for (int q = 0; q < 4; ++q)
                *(float4*)&hb[q][bufrow][cc0] = z4;
            return;
        }
        const int gc0 = c0 - 8 + cc0;   // first of 20 raw cols
        float wx[20], wy[20];
        if (icol) {
            const float* __restrict__ px = xb + grow * IMG + gc0;
            const float* __restrict__ py = yb + grow * IMG + gc0;
#pragma unroll
            for (int i = 0; i < 5; ++i) {
                float4 fx = *(const float4*)(px + 4 * i);
                float4 fy = *(const float4*)(py + 4 * i);
                wx[4*i+0] = fx.x; wx[4*i+1] = fx.y; wx[4*i+2] = fx.z; wx[4*i+3] = fx.w;
                wy[4*i+0] = fy.x; wy[4*i+1] = fy.y; wy[4*i+2] = fy.z; wy[4*i+3] = fy.w;
            }
        } else {
            const float* __restrict__ px = xb + grow * IMG;
            const float* __restrict__ py = yb + grow * IMG;
#pragma unroll
            for (int i = 0; i < 5; ++i) {
                int gc = gc0 + 4 * i;
                if (gc >= 0 && gc + 3 < IMG) {
                    float4 fx = *(const float4*)(px + gc);
                    float4 fy = *(const float4*)(py + gc);
                    wx[4*i+0] = fx.x; wx[4*i+1] = fx.y; wx[4*i+2] = fx.z; wx[4*i+3] = fx.w;
                    wy[4*i+0] = fy.x; wy[4*i+1] = fy.y; wy[4*i+2] = fy.z; wy[4*i+3] = fy.w;
                } else {
#pragma unroll
                    for (int e = 0; e < 4; ++e) {
                        int c = gc + e;
                        bool ok = ((unsigned)c < IMG);
                        wx[4*i+e] = ok ? px[c] : 0.f;
                        wy[4*i+e] = ok ? py[c] : 0.f;
                    }
                }
            }
        }
        float pss[14], pxy[14];         // shared products, raw cols 3..16
#pragma unroll
        for (int j = 0; j < 14; ++j) {
            float a = wx[j + 3], b = wy[j + 3];
            pss[j] = fmaf(a, a, b * b);
            pxy[j] = a * b;
        }
        float ax[4] = {}, ay[4] = {}, ass[4] = {}, axy[4] = {};
#pragma unroll
        for (int e = 0; e < 4; ++e)
#pragma unroll
            for (int k = 0; k < 11; ++k) {
                ax[e]  = fmaf(G[k], wx[e + k + 3], ax[e]);
                ay[e]  = fmaf(G[k], wy[e + k + 3], ay[e]);
                ass[e] = fmaf(G[k], pss[e + k], ass[e]);
                axy[e] = fmaf(G[k], pxy[e + k], axy[e]);
            }
        *(float4*)&hb[0][bufrow][cc0] = make_float4(ax[0], ax[1], ax[2], ax[3]);
        *(float4*)&hb[1][bufrow][cc0] = make_float4(ay[0], ay[1], ay[2], ay[3]);
        *(float4*)&hb[2][bufrow][cc0] = make_float4(ass[0], ass[1], ass[2], ass[3]);
        *(float4*)&hb[3][bufrow][cc0] = make_float4(axy[0], axy[1], axy[2], axy[3]);
    };

    const int cg = tid & 31;            // col pair: cols 2cg, 2cg+1
    const int rb = (tid >> 5) * 4;      // v-pass rows rb..rb+3
    float lsum = 0.f;

    for (int s = 0; s < NSTRIP; ++s) {
        const int sbase = rbase0 + 32 * s;
        if (s == 0) {
            // fill all 42 buffer rows: 672 tasks (16 groups x 42 rows)
            htask(tid >> 4, sbase - 5 + (tid >> 4), tid & 15);
            {
                int t = tid + 256;
                htask(t >> 4, sbase - 5 + (t >> 4), t & 15);
            }
            if (tid < 160) {
                int t = tid + 512;
                htask(t >> 4, sbase - 5 + (t >> 4), t & 15);
            }
        } else {
            // carry rows 32..41 -> 0..9 : 640 float4 moves
#pragma unroll
            for (int k = 0; k < 3; ++k) {
                int idx = tid + k * 256;
                if (idx < 640) {
                    int q = idx / 160, rem = idx - q * 160;
                    int rr = rem >> 4, c4 = rem & 15;
                    *(float4*)&hb[q][rr][4 * c4] =
                        *(const float4*)&hb[q][32 + rr][4 * c4];
                }
            }
            __syncthreads();
            // 32 new h-rows into buffer rows 10..41: exactly 2 tasks/thread
            htask(10 + (tid >> 4), sbase + 5 + (tid >> 4), tid & 15);
            htask(26 + (tid >> 4), sbase + 21 + (tid >> 4), tid & 15);
        }
        __syncthreads();

        // v-pass: 2 cols x 4 rows per thread, float2 LDS reads
        float vr[4][4][2];
#pragma unroll
        for (int q = 0; q < 4; ++q)
#pragma unroll
            for (int j = 0; j < 4; ++j) { vr[q][j][0] = 0.f; vr[q][j][1] = 0.f; }
#pragma unroll
        for (int q = 0; q < 4; ++q)
#pragma unroll
            for (int k = 0; k < 14; ++k) {
                float2 v = *(const float2*)&hb[q][rb + k][2 * cg];
#pragma unroll
                for (int j = 0; j < 4; ++j)
                    if (k - j >= 0 && k - j <= 10) {
                        vr[q][j][0] = fmaf(G[k - j], v.x, vr[q][j][0]);
                        vr[q][j][1] = fmaf(G[k - j], v.y, vr[q][j][1]);
                    }
            }
#pragma unroll
        for (int j = 0; j < 4; ++j)
#pragma unroll
            for (int e = 0; e < 2; ++e) {
                float mx = vr[0][j][e], my = vr[1][j][e];
                float mss = vr[2][j][e], mxy = vr[3][j][e];
                float mx2 = mx * mx, my2 = my * my, mxmy = mx * my;
                float num = (2.f * mxmy + 0.0001f) * (2.f * (mxy - mxmy) + 0.0009f);
                float den = (mx2 + my2 + 0.0001f) * ((mss - mx2 - my2) + 0.0009f);
                lsum += num * __builtin_amdgcn_rcpf(den);
            }
        __syncthreads();   // protect window before next strip's carry
    }

    // ---- block reduction -> plain store ----
#pragma unroll
    for (int off = 32; off > 0; off >>= 1)
        lsum += __shfl_down(lsum, off, 64);
    if ((tid & 63) == 0) wsum[tid >> 6] = lsum;
    __syncthreads();
    if (tid == 0) {
        float ssum = wsum[0] + wsum[1] + wsum[2] + wsum[3];
        int bid = bx + 8 * (by + 2 * blockIdx.z);
        partial[bid] = ssum;
    }
}

__global__ __launch_bounds__(1024) void ssim_reduce_kernel(
    const float* __restrict__ partial, float* __restrict__ out)
{
    __shared__ double ws[16];
    const int tid = threadIdx.x;
    double s = 0.0;
    for (int i = tid; i < NBLK; i += 1024) s += (double)partial[i];
#pragma unroll
    for (int off = 32; off > 0; off >>= 1)
        s += __shfl_down(s, off, 64);
    if ((tid & 63) == 0) ws[tid >> 6] = s;
    __syncthreads();
    if (tid == 0) {
        double t = 0.0;
#pragma unroll
        for (int w = 0; w < 16; ++w) t += ws[w];
        double mean = t / NPIX;
        out[0] = (float)(-log10(mean));  // loss
        out[1] = (float)mean;            // ssim_mean
    }
}

extern "C" void kernel_launch(void* const* d_in, const int* in_sizes, int n_in,
                              void* d_out, int out_size, void* d_ws, size_t ws_size,
                              hipStream_t stream)
{
    const float* x = (const float*)d_in[0];
    const float* y = (const float*)d_in[1];
    float* out     = (float*)d_out;
    float* partial = (float*)d_ws;      // 768 floats, fully rewritten each call

    dim3 grid(8, 2, 48);                // 768 blocks = exactly 3/CU
    ssim_tile_kernel<<<grid, 256, 0, stream>>>(x, y, partial);
    ssim_reduce_kernel<<<1, 1024, 0, stream>>>(partial, out);
}

// Round 11
// 66.286 us; speedup vs baseline: 1.4986x; 1.3136x over previous
//
#include <hip/hip_runtime.h>
#include <math.h>

#define IMG    512
#define TWD    64        // tile width
#define NSTRIP 8         // 32-row strips per block
#define BROWS  256       // output rows per block
#define WIN    42        // rolling hb window rows
#define HS     68        // hb row stride: 272B (16B-aligned), 68%32=4
#define NBLK   768       // 8 * 2 * 48
#define NPIX   12582912.0

// Normalized 11-tap Gaussian, sigma=1.5 — inline literals
constexpr float G[11] = {
    0.00102838f, 0.00759876f, 0.03600077f, 0.10936069f, 0.21300554f,
    0.26601173f,
    0.21300554f, 0.10936069f, 0.03600077f, 0.00759876f, 0.00102838f};

// h-task: 8 outputs (cols 8g..8g+7) of global row grow -> buffer row bufrow.
// FORCED inline: outlined-lambda ABI put the arrays in scratch (R8-R10's
// 20-49 MB WRITE_SIZE). In-place wx/wy->product transform keeps peak live
// set ~72 floats.
__device__ __forceinline__ void htask8(
    float (&hb)[4][WIN][HS],
    const float* __restrict__ xb, const float* __restrict__ yb,
    int c0, bool icol, int bufrow, int grow, int g)
{
    const int cc0 = 8 * g;
    if ((unsigned)grow >= IMG) {        // zero-pad rows outside image
        float4 z4 = make_float4(0.f, 0.f, 0.f, 0.f);
#pragma unroll
        for (int q = 0; q < 4; ++q) {
            *(float4*)&hb[q][bufrow][cc0]     = z4;
            *(float4*)&hb[q][bufrow][cc0 + 4] = z4;
        }
        return;
    }
    const int gc0 = c0 - 8 + cc0;       // first of 24 raw cols
    float wx[24], wy[24];
    if (icol) {
        const float* __restrict__ px = xb + grow * IMG + gc0;
        const float* __restrict__ py = yb + grow * IMG + gc0;
#pragma unroll
        for (int i = 0; i < 6; ++i) {
            float4 fx = *(const float4*)(px + 4 * i);
            float4 fy = *(const float4*)(py + 4 * i);
            wx[4*i+0] = fx.x; wx[4*i+1] = fx.y; wx[4*i+2] = fx.z; wx[4*i+3] = fx.w;
            wy[4*i+0] = fy.x; wy[4*i+1] = fy.y; wy[4*i+2] = fy.z; wy[4*i+3] = fy.w;
        }
    } else {
        const float* __restrict__ px = xb + grow * IMG;
        const float* __restrict__ py = yb + grow * IMG;
#pragma unroll
        for (int i = 0; i < 6; ++i) {
            int gc = gc0 + 4 * i;
            if (gc >= 0 && gc + 3 < IMG) {
                float4 fx = *(const float4*)(px + gc);
                float4 fy = *(const float4*)(py + gc);
                wx[4*i+0] = fx.x; wx[4*i+1] = fx.y; wx[4*i+2] = fx.z; wx[4*i+3] = fx.w;
                wy[4*i+0] = fy.x; wy[4*i+1] = fy.y; wy[4*i+2] = fy.z; wy[4*i+3] = fy.w;
            } else {
#pragma unroll
                for (int e = 0; e < 4; ++e) {
                    int c = gc + e;
                    bool ok = ((unsigned)c < IMG);
                    wx[4*i+e] = ok ? px[c] : 0.f;
                    wy[4*i+e] = ok ? py[c] : 0.f;
                }
            }
        }
    }
    // ---- means first (consume raw wx/wy) ----
    float ax[8] = {}, ay[8] = {};
#pragma unroll
    for (int e = 0; e < 8; ++e)
#pragma unroll
        for (int k = 0; k < 11; ++k) {
            ax[e] = fmaf(G[k], wx[e + k + 3], ax[e]);
            ay[e] = fmaf(G[k], wy[e + k + 3], ay[e]);
        }
    *(float4*)&hb[0][bufrow][cc0]     = make_float4(ax[0], ax[1], ax[2], ax[3]);
    *(float4*)&hb[0][bufrow][cc0 + 4] = make_float4(ax[4], ax[5], ax[6], ax[7]);
    *(float4*)&hb[1][bufrow][cc0]     = make_float4(ay[0], ay[1], ay[2], ay[3]);
    *(float4*)&hb[1][bufrow][cc0 + 4] = make_float4(ay[4], ay[5], ay[6], ay[7]);
    // ---- in-place transform to products for cols 3..20 ----
#pragma unroll
    for (int j = 3; j < 21; ++j) {
        float a = wx[j], b = wy[j];
        wx[j] = fmaf(a, a, b * b);      // x^2 + y^2
        wy[j] = a * b;                  // x*y
    }
    float ass[8] = {}, axy[8] = {};
#pragma unroll
    for (int e = 0; e < 8; ++e)
#pragma unroll
        for (int k = 0; k < 11; ++k) {
            ass[e] = fmaf(G[k], wx[e + k + 3], ass[e]);
            axy[e] = fmaf(G[k], wy[e + k + 3], axy[e]);
        }
    *(float4*)&hb[2][bufrow][cc0]     = make_float4(ass[0], ass[1], ass[2], ass[3]);
    *(float4*)&hb[2][bufrow][cc0 + 4] = make_float4(ass[4], ass[5], ass[6], ass[7]);
    *(float4*)&hb[3][bufrow][cc0]     = make_float4(axy[0], axy[1], axy[2], axy[3]);
    *(float4*)&hb[3][bufrow][cc0 + 4] = make_float4(axy[4], axy[5], axy[6], axy[7]);
}

// hb planes: 0=mean(x) 1=mean(y) 2=mean(x^2+y^2) 3=mean(xy)
// buffer row b holds h-conv of global row (strip_base - 5 + b)
__global__ __launch_bounds__(256, 3) void ssim_tile_kernel(
    const float* __restrict__ x, const float* __restrict__ y,
    float* __restrict__ partial)
{
    __shared__ float hb[4][WIN][HS];    // 45.7 KB -> 3 blocks/CU
    __shared__ float wsum[4];

    const int tid = threadIdx.x;
    const int bx = blockIdx.x, by = blockIdx.y;
    const int c0 = bx * TWD;
    const int rbase0 = by * BROWS;
    const size_t ioff = (size_t)blockIdx.z * IMG * IMG;
    const float* __restrict__ xb = x + ioff;
    const float* __restrict__ yb = y + ioff;

    const bool icol = (bx > 0) & (bx < 7);

    const int cg = tid & 31;            // column pair: cols 2cg, 2cg+1
    const int rb = (tid >> 5) * 4;      // v-pass rows rb..rb+3
    float lsum = 0.f;

    for (int s = 0; s < NSTRIP; ++s) {
        const int sbase = rbase0 + 32 * s;
        if (s == 0) {
            // fill all 42 buffer rows: 336 tasks (8 groups x 42 rows)
            htask8(hb, xb, yb, c0, icol, tid >> 3, sbase - 5 + (tid >> 3), tid & 7);
            if (tid < 80) {
                int t = tid + 256;
                htask8(hb, xb, yb, c0, icol, t >> 3, sbase - 5 + (t >> 3), t & 7);
            }
        } else {
            // carry rows 32..41 -> 0..9 : 640 float4 moves
#pragma unroll
            for (int k = 0; k < 3; ++k) {
                int idx = tid + k * 256;
                if (idx < 640) {
                    int q = idx / 160, rem = idx - q * 160;
                    int rr = rem >> 4, c4 = rem & 15;
                    *(float4*)&hb[q][rr][4 * c4] =
                        *(const float4*)&hb[q][32 + rr][4 * c4];
                }
            }
            __syncthreads();
            // 32 new h-rows into buffer rows 10..41: exactly 1 task/thread
            htask8(hb, xb, yb, c0, icol, 10 + (tid >> 3), sbase + 5 + (tid >> 3), tid & 7);
        }
        __syncthreads();

        // v-pass: 2 cols x 4 rows per thread, float2 LDS reads
        float vr[4][4][2];
#pragma unroll
        for (int q = 0; q < 4; ++q)
#pragma unroll
            for (int j = 0; j < 4; ++j) { vr[q][j][0] = 0.f; vr[q][j][1] = 0.f; }
#pragma unroll
        for (int q = 0; q < 4; ++q)
#pragma unroll
            for (int k = 0; k < 14; ++k) {
                float2 v = *(const float2*)&hb[q][rb + k][2 * cg];
#pragma unroll
                for (int j = 0; j < 4; ++j)
                    if (k - j >= 0 && k - j <= 10) {
                        vr[q][j][0] = fmaf(G[k - j], v.x, vr[q][j][0]);
                        vr[q][j][1] = fmaf(G[k - j], v.y, vr[q][j][1]);
                    }
            }
#pragma unroll
        for (int j = 0; j < 4; ++j)
#pragma unroll
            for (int e = 0; e < 2; ++e) {
                float mx = vr[0][j][e], my = vr[1][j][e];
                float mss = vr[2][j][e], mxy = vr[3][j][e];
                float mx2 = mx * mx, my2 = my * my, mxmy = mx * my;
                float num = (2.f * mxmy + 0.0001f) * (2.f * (mxy - mxmy) + 0.0009f);
                float den = (mx2 + my2 + 0.0001f) * ((mss - mx2 - my2) + 0.0009f);
                lsum += num * __builtin_amdgcn_rcpf(den);
            }
        __syncthreads();   // protect window before next strip's carry
    }

    // ---- block reduction -> plain store ----
#pragma unroll
    for (int off = 32; off > 0; off >>= 1)
        lsum += __shfl_down(lsum, off, 64);
    if ((tid & 63) == 0) wsum[tid >> 6] = lsum;
    __syncthreads();
    if (tid == 0) {
        float ssum = wsum[0] + wsum[1] + wsum[2] + wsum[3];
        int bid = bx + 8 * (by + 2 * blockIdx.z);
        partial[bid] = ssum;
    }
}

__global__ __launch_bounds__(1024) void ssim_reduce_kernel(
    const float* __restrict__ partial, float* __restrict__ out)
{
    __shared__ double ws[16];
    const int tid = threadIdx.x;
    double s = 0.0;
    for (int i = tid; i < NBLK; i += 1024) s += (double)partial[i];
#pragma unroll
    for (int off = 32; off > 0; off >>= 1)
        s += __shfl_down(s, off, 64);
    if ((tid & 63) == 0) ws[tid >> 6] = s;
    __syncthreads();
    if (tid == 0) {
        double t = 0.0;
#pragma unroll
        for (int w = 0; w < 16; ++w) t += ws[w];
        double mean = t / NPIX;
        out[0] = (float)(-log10(mean));  // loss
        out[1] = (float)mean;            // ssim_mean
    }
}

extern "C" void kernel_launch(void* const* d_in, const int* in_sizes, int n_in,
                              void* d_out, int out_size, void* d_ws, size_t ws_size,
                              hipStream_t stream)
{
    const float* x = (const float*)d_in[0];
    const float* y = (const float*)d_in[1];
    float* out     = (float*)d_out;
    float* partial = (float*)d_ws;      // 768 floats, fully rewritten each call

    dim3 grid(8, 2, 48);                // 768 blocks = exactly 3/CU
    ssim_tile_kernel<<<grid, 256, 0, stream>>>(x, y, partial);
    ssim_reduce_kernel<<<1, 1024, 0, stream>>>(partial, out);
}